// Round 11
// baseline (329.324 us; speedup 1.0000x reference)
//
#include <hip/hip_runtime.h>
#include <math.h>

#define HW    65536      // H*W
#define EPSLN 1e-5f

typedef unsigned short ushort_t;
typedef __attribute__((ext_vector_type(8))) short bf16x8;
typedef __attribute__((ext_vector_type(4))) short bf16x4;
typedef __attribute__((ext_vector_type(4))) float f32x4;

// ws layout (ushort units): [0, QKV_USHORTS) = qkv bf16 [B][12][HW][16], then weights
#define QKV_USHORTS (4*192*65536)
#define WQ_H 0
#define WQ_L 12288
#define W1_H 24576
#define W1_L 40960
#define W2_H 57344
#define W2_L 73728
#define WO_H 90112
#define WO_L 94208

__device__ __forceinline__ ushort_t f2bf(float f) {
    unsigned u = __float_as_uint(f);
    return (ushort_t)((u + 0x7FFFu + ((u >> 16) & 1u)) >> 16);   // RNE
}
__device__ __forceinline__ float bf2f(ushort_t h) {
    return __uint_as_float(((unsigned)h) << 16);
}
// tanh-based GELU: 1 exp + 1 rcp, |err| ~1e-3 abs
__device__ __forceinline__ float gelu_fast(float v) {
    float u  = v * v * v;
    float z2 = 1.5957691216057308f * v + 0.07135481627283788f * u;
    float e  = __expf(z2);
    float th = 1.f - 2.f * __builtin_amdgcn_rcpf(1.f + e);
    return 0.5f * v * (1.f + th);
}

// ---------------------------------------------------------------------------
// Prep: split all weights into bf16 hi/lo.
// ---------------------------------------------------------------------------
__global__ void k_prep(const float* __restrict__ wq, const float* __restrict__ w1,
                       const float* __restrict__ w2, const float* __restrict__ wo,
                       ushort_t* __restrict__ wb)
{
    int i = blockIdx.x * 256 + threadIdx.x;   // 0..49151
    float v; int oh, ol;
    if (i < 12288)      { v = wq[i];          oh = WQ_H + i;          ol = WQ_L + i; }
    else if (i < 28672) { int j = i - 12288;  v = w1[j]; oh = W1_H+j; ol = W1_L+j; }
    else if (i < 45056) { int j = i - 28672;  v = w2[j]; oh = W2_H+j; ol = W2_L+j; }
    else                { int j = i - 45056;  v = wo[j]; oh = WO_H+j; ol = WO_L+j; }
    ushort_t h = f2bf(v);
    wb[oh] = h;
    wb[ol] = f2bf(v - bf2f(h));
}

// ---------------------------------------------------------------------------
// Kernel 1: LN1 + QKV (64->192) via MFMA. 1 wave/block, 64 px/wave.
// qkv stored bf16 [B][12][HW][16] d-contiguous.
// ---------------------------------------------------------------------------
__global__ __launch_bounds__(64, 5) void k_lnqkv_mfma(
    const float* __restrict__ x,  const float* __restrict__ g1,
    const float* __restrict__ b1, const ushort_t* __restrict__ wb,
    const float* __restrict__ bq, ushort_t* __restrict__ qkv)
{
    __shared__ float sg1[64], sb1[64], sbq[192];
    int tid = threadIdx.x;
    sg1[tid] = g1[tid]; sb1[tid] = b1[tid];
#pragma unroll
    for (int i = tid; i < 192; i += 64) sbq[i] = bq[i];
    __syncthreads();

    int lane = tid;
    int g = lane >> 4, q = lane & 15;
    int px0 = blockIdx.x * 64;
    int b   = px0 >> 16;
    int hwb = px0 & 65535;
    const float* xb = x + (size_t)b * 64 * HW;

    bf16x8 bh[4][2];
#pragma unroll
    for (int pg = 0; pg < 4; ++pg) {
        int hw = hwb + pg * 16 + q;
        const float* xp = xb + hw;
        float xv[16];
#pragma unroll
        for (int j = 0; j < 8; ++j) {
            xv[j]     = xp[(g * 8 + j) * HW];
            xv[8 + j] = xp[(32 + g * 8 + j) * HW];
        }
        float s = 0.f;
#pragma unroll
        for (int j = 0; j < 16; ++j) s += xv[j];
        s += __shfl_xor(s, 16); s += __shfl_xor(s, 32);
        float mu = s * 0.015625f;
        float s2 = 0.f;
#pragma unroll
        for (int j = 0; j < 16; ++j) { float d = xv[j] - mu; s2 += d * d; }
        s2 += __shfl_xor(s2, 16); s2 += __shfl_xor(s2, 32);
        float inv = rsqrtf(s2 * 0.015625f + EPSLN);
#pragma unroll
        for (int kt = 0; kt < 2; ++kt)
#pragma unroll
            for (int j = 0; j < 8; ++j) {
                int c = kt * 32 + g * 8 + j;
                float f = (xv[kt * 8 + j] - mu) * inv * sg1[c] + sb1[c];
                bh[pg][kt][j] = (short)f2bf(f);
            }
    }

    const ushort_t* wqh = wb + WQ_H;
    const ushort_t* wql = wb + WQ_L;
    ushort_t* outb = qkv + (size_t)b * 12 * HW * 16;

#pragma unroll 2
    for (int mt = 0; mt < 12; ++mt) {
        bf16x8 ah[2], al[2];
#pragma unroll
        for (int kt = 0; kt < 2; ++kt) {
            ah[kt] = *(const bf16x8*)(wqh + (mt * 16 + q) * 64 + kt * 32 + g * 8);
            al[kt] = *(const bf16x8*)(wql + (mt * 16 + q) * 64 + kt * 32 + g * 8);
        }
        f32x4 bias = *(const f32x4*)(&sbq[mt * 16 + 4 * g]);
#pragma unroll
        for (int pg = 0; pg < 4; ++pg) {
            f32x4 d = bias;
#pragma unroll
            for (int kt = 0; kt < 2; ++kt) {
                d = __builtin_amdgcn_mfma_f32_16x16x32_bf16(ah[kt], bh[pg][kt], d, 0, 0, 0);
                d = __builtin_amdgcn_mfma_f32_16x16x32_bf16(al[kt], bh[pg][kt], d, 0, 0, 0);
            }
            bf16x4 st;
#pragma unroll
            for (int i = 0; i < 4; ++i) st[i] = (short)f2bf(d[i]);
            int hw = hwb + pg * 16 + q;
            *(bf16x4*)(outb + ((size_t)mt * HW + hw) * 16 + 4 * g) = st;
        }
    }
}

// ---------------------------------------------------------------------------
// Kernel 2 (FUSED): neighborhood attention + out-proj + residual (x1 in
// REGISTERS) + LN2 + FC1 + GELU + FC2 + GELU + residual -> out.
// 1 wave/block, 64 px. x1 never touches global memory.
// LDS: 8 KB retile buffer (abuf -> x1-retile -> h-retile) + biases.
// ---------------------------------------------------------------------------
__global__ __launch_bounds__(64, 2) void k_attn_mlp(
    const float* __restrict__ x, const ushort_t* __restrict__ qkv,
    const ushort_t* __restrict__ wb, const float* __restrict__ bo,
    const float* __restrict__ g2, const float* __restrict__ b2,
    const float* __restrict__ bb1, const float* __restrict__ bb2,
    float* __restrict__ out)
{
    __shared__ ushort_t lds[4096];   // abuf / x1-retile / h-retile (reused)
    __shared__ float sbo[64], sg2[64], sb2[64], sbb1[256], sbb2[64];
    int lane = threadIdx.x;
    sbo[lane] = bo[lane]; sg2[lane] = g2[lane];
    sb2[lane] = b2[lane]; sbb2[lane] = bb2[lane];
#pragma unroll
    for (int i = lane; i < 256; i += 64) sbb1[i] = bb1[i];
    __syncthreads();

    int px = blockIdx.x * 64 + lane;
    int b = px >> 16, hw = px & 65535;
    int hh = hw >> 8, ww = hw & 255;
    const ushort_t* tb = qkv + (size_t)b * 12 * HW * 16;

    // ---------------- attention core ----------------
    int   nidx[9];
    float nmask[9];
#pragma unroll
    for (int n = 0; n < 9; ++n) {
        int dy = (n / 3) * 2 - 2, dx = (n % 3) * 2 - 2;
        int y = hh + dy, xw = ww + dx;
        int yc = min(max(y, 0), 255), xc = min(max(xw, 0), 255);
        nidx[n]  = yc * 256 + xc;
        nmask[n] = (y == yc && xw == xc) ? 1.f : 0.f;
    }

#pragma unroll 1
    for (int head = 0; head < 4; ++head) {
        const ushort_t* qp = tb + ((size_t)head * HW + hw) * 16;
        bf16x8 q0 = *(const bf16x8*)qp;
        bf16x8 q1 = *(const bf16x8*)(qp + 8);
        float qv[16];
#pragma unroll
        for (int j = 0; j < 8; ++j) {
            qv[j]     = bf2f((ushort_t)q0[j]) * 0.25f;
            qv[8 + j] = bf2f((ushort_t)q1[j]) * 0.25f;
        }
        const ushort_t* kb = tb + (size_t)(4 + head) * HW * 16;
        const ushort_t* vb = tb + (size_t)(8 + head) * HW * 16;

        float sc[9];
#pragma unroll
        for (int n = 0; n < 9; ++n) {
            const ushort_t* kp = kb + (size_t)nidx[n] * 16;
            bf16x8 k0 = *(const bf16x8*)kp;
            bf16x8 k1 = *(const bf16x8*)(kp + 8);
            float s = 0.f;
#pragma unroll
            for (int j = 0; j < 8; ++j) {
                s += qv[j]     * bf2f((ushort_t)k0[j]);
                s += qv[8 + j] * bf2f((ushort_t)k1[j]);
            }
            sc[n] = s * nmask[n];
        }
        float mx = sc[0];
#pragma unroll
        for (int n = 1; n < 9; ++n) mx = fmaxf(mx, sc[n]);

        float ew[9], sum = 0.f;
#pragma unroll
        for (int n = 0; n < 9; ++n) {
            float e = __expf(sc[n] - mx);
            sum += e;
            ew[n] = e * nmask[n];
        }

        float o16[16];
#pragma unroll
        for (int d = 0; d < 16; ++d) o16[d] = 0.f;
#pragma unroll
        for (int n = 0; n < 9; ++n) {
            const ushort_t* vp = vb + (size_t)nidx[n] * 16;
            bf16x8 v0 = *(const bf16x8*)vp;
            bf16x8 v1 = *(const bf16x8*)(vp + 8);
            float a = ew[n];
#pragma unroll
            for (int j = 0; j < 8; ++j) {
                o16[j]     += a * bf2f((ushort_t)v0[j]);
                o16[8 + j] += a * bf2f((ushort_t)v1[j]);
            }
        }
        float isum = __builtin_amdgcn_rcpf(sum);

        bf16x8 w0, w1v;
#pragma unroll
        for (int j = 0; j < 8; ++j) {
            w0[j]  = (short)f2bf(o16[j] * isum);
            w1v[j] = (short)f2bf(o16[8 + j] * isum);
        }
        int c0 = (head * 2)     ^ (lane & 7);
        int c1 = (head * 2 + 1) ^ (lane & 7);
        *(bf16x8*)(&lds[lane * 64 + c0 * 8]) = w0;
        *(bf16x8*)(&lds[lane * 64 + c1 * 8]) = w1v;
    }
    __syncthreads();

    int g = lane >> 4, q = lane & 15;
    int hwb = (blockIdx.x * 64) & 65535;
    const float* xb = x + (size_t)b * 64 * HW;

    // attnout B-frags from abuf
    bf16x8 bbf[4][2];
#pragma unroll
    for (int pg = 0; pg < 4; ++pg) {
        int r = pg * 16 + q;
#pragma unroll
        for (int kt = 0; kt < 2; ++kt) {
            int c = (kt * 4 + g) ^ (r & 7);
            bbf[pg][kt] = *(const bf16x8*)(&lds[r * 64 + c * 8]);
        }
    }

    // ---------------- out-proj + residual: x1 in registers ----------------
    const ushort_t* woh = wb + WO_H;
    const ushort_t* wol = wb + WO_L;
    f32x4 x1r[4][4];   // [pg][mt]: ch = mt*16+4g+i, px = hwb+pg*16+q
#pragma unroll 1
    for (int mt = 0; mt < 4; ++mt) {
        bf16x8 ah[2], al[2];
#pragma unroll
        for (int kt = 0; kt < 2; ++kt) {
            ah[kt] = *(const bf16x8*)(woh + (mt * 16 + q) * 64 + kt * 32 + g * 8);
            al[kt] = *(const bf16x8*)(wol + (mt * 16 + q) * 64 + kt * 32 + g * 8);
        }
        f32x4 bias = *(const f32x4*)(&sbo[mt * 16 + 4 * g]);
#pragma unroll
        for (int pg = 0; pg < 4; ++pg) {
            f32x4 d = bias;
#pragma unroll
            for (int kt = 0; kt < 2; ++kt) {
                d = __builtin_amdgcn_mfma_f32_16x16x32_bf16(ah[kt], bbf[pg][kt], d, 0, 0, 0);
                d = __builtin_amdgcn_mfma_f32_16x16x32_bf16(al[kt], bbf[pg][kt], d, 0, 0, 0);
            }
            int hwg = hwb + pg * 16 + q;
#pragma unroll
            for (int i = 0; i < 4; ++i) {
                int o = mt * 16 + 4 * g + i;
                x1r[pg][mt][i] = xb[(size_t)o * HW + hwg] + d[i];
            }
        }
    }
    __syncthreads();   // abuf reads done; safe to reuse lds for x1-retile

    // ---------------- LN2 on x1 (registers) + retile to B-frags ----------
    // lds x1-retile: row r=pg*16+q (64 rows x 64ch), 4-ushort chunks,
    // chunk position = (mt*4+g) ^ (q&6)  (order-preserving for 8-ushort reads)
#pragma unroll
    for (int pg = 0; pg < 4; ++pg) {
        float s = 0.f;
#pragma unroll
        for (int mt = 0; mt < 4; ++mt)
#pragma unroll
            for (int i = 0; i < 4; ++i) s += x1r[pg][mt][i];
        s += __shfl_xor(s, 16); s += __shfl_xor(s, 32);
        float mu = s * 0.015625f;
        float s2 = 0.f;
#pragma unroll
        for (int mt = 0; mt < 4; ++mt)
#pragma unroll
            for (int i = 0; i < 4; ++i) { float d = x1r[pg][mt][i] - mu; s2 += d * d; }
        s2 += __shfl_xor(s2, 16); s2 += __shfl_xor(s2, 32);
        float inv = rsqrtf(s2 * 0.015625f + EPSLN);

        int r = pg * 16 + q;
#pragma unroll
        for (int mt = 0; mt < 4; ++mt) {
            bf16x4 st;
#pragma unroll
            for (int i = 0; i < 4; ++i) {
                int c = mt * 16 + 4 * g + i;
                float f = (x1r[pg][mt][i] - mu) * inv * sg2[c] + sb2[c];
                st[i] = (short)f2bf(f);
            }
            int chunk = (mt * 4 + g) ^ (q & 6);
            *(bf16x4*)(&lds[r * 64 + chunk * 4]) = st;
        }
    }
    __syncthreads();

    bf16x8 bh[4][2];
#pragma unroll
    for (int pg = 0; pg < 4; ++pg) {
        int r = pg * 16 + q;
#pragma unroll
        for (int kt = 0; kt < 2; ++kt) {
            int c0 = (kt * 8 + 2 * g) ^ (q & 6);
            bh[pg][kt] = *(const bf16x8*)(&lds[r * 64 + c0 * 4]);
        }
    }
    __syncthreads();   // x1-retile reads done; lds now reused as h-retile

    // ---------------- MLP: FC1+GELU -> FC2 (+GELU) + residual -------------
    const ushort_t* w1h = wb + W1_H;  const ushort_t* w1l = wb + W1_L;
    const ushort_t* w2h = wb + W2_H;  const ushort_t* w2l = wb + W2_L;

    f32x4 acc2[4][4];   // [pg][m2]
#pragma unroll
    for (int m2 = 0; m2 < 4; ++m2) {
        f32x4 binit = *(const f32x4*)(&sbb2[m2 * 16 + 4 * g]);
#pragma unroll
        for (int pg = 0; pg < 4; ++pg) acc2[pg][m2] = binit;
    }

#pragma unroll 1
    for (int mtp = 0; mtp < 8; ++mtp) {
        int buf = mtp & 1;
#pragma unroll
        for (int e = 0; e < 2; ++e) {
            int mt = mtp * 2 + e;
            bf16x8 ah[2], al[2];
#pragma unroll
            for (int kt = 0; kt < 2; ++kt) {
                ah[kt] = *(const bf16x8*)(w1h + (mt * 16 + q) * 64 + kt * 32 + g * 8);
                al[kt] = *(const bf16x8*)(w1l + (mt * 16 + q) * 64 + kt * 32 + g * 8);
            }
            f32x4 b1v = *(const f32x4*)(&sbb1[mt * 16 + 4 * g]);
            int chunk = (e * 4 + g) ^ (q & 6);
#pragma unroll
            for (int pg = 0; pg < 4; ++pg) {
                f32x4 d = b1v;
#pragma unroll
                for (int kt = 0; kt < 2; ++kt) {
                    d = __builtin_amdgcn_mfma_f32_16x16x32_bf16(ah[kt], bh[pg][kt], d, 0, 0, 0);
                    d = __builtin_amdgcn_mfma_f32_16x16x32_bf16(al[kt], bh[pg][kt], d, 0, 0, 0);
                }
                bf16x4 vh;
#pragma unroll
                for (int i = 0; i < 4; ++i)
                    vh[i] = (short)f2bf(gelu_fast(d[i]));
                *(bf16x4*)(&lds[buf * 2048 + pg * 512 + q * 32 + chunk * 4]) = vh;
            }
        }
        // FC2: consume this 32-h slice
        int c0 = (2 * g) ^ (q & 6);
        bf16x8 p2[4];
#pragma unroll
        for (int pg = 0; pg < 4; ++pg)
            p2[pg] = *(const bf16x8*)(&lds[buf * 2048 + pg * 512 + q * 32 + c0 * 4]);
#pragma unroll
        for (int m2 = 0; m2 < 4; ++m2) {
            bf16x8 ah2 = *(const bf16x8*)(w2h + (m2 * 16 + q) * 256 + mtp * 32 + g * 8);
            bf16x8 al2 = *(const bf16x8*)(w2l + (m2 * 16 + q) * 256 + mtp * 32 + g * 8);
#pragma unroll
            for (int pg = 0; pg < 4; ++pg) {
                acc2[pg][m2] = __builtin_amdgcn_mfma_f32_16x16x32_bf16(ah2, p2[pg], acc2[pg][m2], 0, 0, 0);
                acc2[pg][m2] = __builtin_amdgcn_mfma_f32_16x16x32_bf16(al2, p2[pg], acc2[pg][m2], 0, 0, 0);
            }
        }
    }

    // ---------------- epilogue: out = x1 + gelu(fc2) ----------------------
    float* ob = out + (size_t)b * 64 * HW;
#pragma unroll
    for (int pg = 0; pg < 4; ++pg) {
        int hwg = hwb + pg * 16 + q;
#pragma unroll
        for (int m2 = 0; m2 < 4; ++m2)
#pragma unroll
            for (int i = 0; i < 4; ++i) {
                int o = m2 * 16 + 4 * g + i;
                float m = gelu_fast(acc2[pg][m2][i]);
                ob[(size_t)o * HW + hwg] = x1r[pg][m2][i] + m;
            }
    }
}

// ---------------------------------------------------------------------------
extern "C" void kernel_launch(void* const* d_in, const int* in_sizes, int n_in,
                              void* d_out, int out_size, void* d_ws, size_t ws_size,
                              hipStream_t stream)
{
    const float* x     = (const float*)d_in[0];
    const float* g1    = (const float*)d_in[1];
    const float* b1    = (const float*)d_in[2];
    const float* g2    = (const float*)d_in[3];
    const float* b2    = (const float*)d_in[4];
    const float* w_qkv = (const float*)d_in[5];
    const float* b_qkv = (const float*)d_in[6];
    const float* w_out = (const float*)d_in[7];
    const float* b_out = (const float*)d_in[8];
    const float* w1    = (const float*)d_in[9];
    const float* bb1   = (const float*)d_in[10];
    const float* w2    = (const float*)d_in[11];
    const float* bb2   = (const float*)d_in[12];

    float*    out = (float*)d_out;
    ushort_t* qkv = (ushort_t*)d_ws;                 // bf16 qkv, 96 MiB
    ushort_t* wb  = (ushort_t*)d_ws + QKV_USHORTS;   // bf16 hi/lo weights

    k_prep      <<<192,  256, 0, stream>>>(w_qkv, w1, w2, w_out, wb);
    k_lnqkv_mfma<<<4096, 64, 0, stream>>>(x, g1, b1, wb, b_qkv, qkv);
    k_attn_mlp  <<<4096, 64, 0, stream>>>(x, qkv, wb, b_out, g2, b2, bb1, bb2, out);
}